// Round 4
// baseline (879.857 us; speedup 1.0000x reference)
//
#include <hip/hip_runtime.h>
#include <hip/hip_bf16.h>

#define NM 128        // n_mentions / queries
#define HD 768        // hidden
#define TT 512        // tokens per batch
#define KD 128        // key dim
#define NROWS 16384   // memory rows
#define VPR 64        // values per row
#define KTOP 32
#define K2_BLOCKS 2048
#define NEG_INF -3.402823466e38f

typedef __bf16 bf16x8 __attribute__((ext_vector_type(8)));
typedef float  f32x4  __attribute__((ext_vector_type(4)));

__device__ __forceinline__ unsigned short f2bf(float f) {
    __bf16 h = (__bf16)f;
    return __builtin_bit_cast(unsigned short, h);
}

// ---------------------------------------------------------------- K1: queries
__global__ __launch_bounds__(256) void k1_queries(
    const float* __restrict__ enc, const int* __restrict__ mb,
    const int* __restrict__ msp, const int* __restrict__ mep,
    const float* __restrict__ qw, const float* __restrict__ qb,
    float* __restrict__ q_f32, unsigned short* __restrict__ q_bf16)
{
    int q = blockIdx.x;
    int b = mb[q], s = msp[q], e = mep[q];
    __shared__ float encs[2 * HD];
    const float* srow = enc + ((size_t)b * TT + s) * HD;
    const float* erow = enc + ((size_t)b * TT + e) * HD;
    for (int i = threadIdx.x; i < HD; i += 256) {
        encs[i]      = srow[i];
        encs[HD + i] = erow[i];
    }
    __syncthreads();
    int d = threadIdx.x & 127;
    int h = threadIdx.x >> 7;           // 0 = start half, 1 = end half
    const float* w  = qw + (size_t)(h * HD) * KD + d;
    const float* ev = encs + h * HD;
    float acc = 0.f;
#pragma unroll 8
    for (int i = 0; i < HD; ++i) acc = fmaf(ev[i], w[(size_t)i * KD], acc);
    __shared__ float part[256];
    part[threadIdx.x] = acc;
    __syncthreads();
    if (threadIdx.x < 128) {
        float v = part[threadIdx.x] + part[threadIdx.x + 128] + qb[d];
        q_f32[q * KD + d] = v;
        // bf16 copy in the (swizzled) LDS A-operand layout K2 will memcpy
        unsigned byteoff = ((unsigned)(q * 256 + d * 2)) ^ (((unsigned)(q & 7)) << 4);
        q_bf16[byteoff >> 1] = f2bf(v);
    }
}

// ------------------------------------------------- K2: scores + row max/argmax
__global__ __launch_bounds__(256) void k2_scores(
    const float* __restrict__ mkeys, const unsigned short* __restrict__ q_bf16,
    float* __restrict__ scores_t, unsigned char* __restrict__ widx_t)
{
    __shared__ __attribute__((aligned(16))) unsigned short qs[NM * KD];  // 32KB swizzled
    __shared__ __attribute__((aligned(16))) unsigned short ks[VPR * KD]; // 16KB swizzled
    {   // queries: global layout already matches LDS layout -> linear copy
        const uint4* src = (const uint4*)q_bf16;
        uint4* dst = (uint4*)qs;
#pragma unroll
        for (int i = 0; i < 8; ++i) dst[i * 256 + threadIdx.x] = src[i * 256 + threadIdx.x];
    }
    int lane = threadIdx.x & 63;
    int wave = threadIdx.x >> 6;

    for (int r = blockIdx.x; r < NROWS; r += K2_BLOCKS) {
        __syncthreads();  // previous iter's reads done (also covers qs copy)
        // ---- stage row r: 64 slots x 128 d fp32 -> bf16 swizzled LDS
        const float4* src = (const float4*)(mkeys + (size_t)r * (VPR * KD));
        float4 v[8];
#pragma unroll
        for (int i = 0; i < 8; ++i) v[i] = src[i * 256 + threadIdx.x];
#pragma unroll
        for (int i = 0; i < 8; ++i) {
            int fidx = (i * 256 + threadIdx.x) * 4;
            int slot = fidx >> 7, dd = fidx & 127;
            ushort4 u;
            u.x = f2bf(v[i].x); u.y = f2bf(v[i].y);
            u.z = f2bf(v[i].z); u.w = f2bf(v[i].w);
            unsigned byteoff = ((unsigned)(slot * 256 + dd * 2)) ^ (((unsigned)(slot & 7)) << 4);
            *(ushort4*)((char*)ks + byteoff) = u;
        }
        __syncthreads();
        // ---- MFMA: wave handles q-tiles {2w,2w+1} x slot-tiles {0..3}
        f32x4 acc[2][4];
        f32x4 zero = {0.f, 0.f, 0.f, 0.f};
#pragma unroll
        for (int qt = 0; qt < 2; ++qt)
#pragma unroll
            for (int st = 0; st < 4; ++st) acc[qt][st] = zero;
#pragma unroll
        for (int kk = 0; kk < 4; ++kk) {
            int kbase = kk * 32 + (lane >> 4) * 8;
            bf16x8 a[2], bb[4];
#pragma unroll
            for (int qt = 0; qt < 2; ++qt) {
                int qrow = (2 * wave + qt) * 16 + (lane & 15);
                unsigned byteoff = ((unsigned)(qrow * 256 + kbase * 2)) ^ (((unsigned)(qrow & 7)) << 4);
                a[qt] = *(const bf16x8*)((const char*)qs + byteoff);
            }
#pragma unroll
            for (int st = 0; st < 4; ++st) {
                int slot = st * 16 + (lane & 15);
                unsigned byteoff = ((unsigned)(slot * 256 + kbase * 2)) ^ (((unsigned)(slot & 7)) << 4);
                bb[st] = *(const bf16x8*)((const char*)ks + byteoff);
            }
#pragma unroll
            for (int qt = 0; qt < 2; ++qt)
#pragma unroll
                for (int st = 0; st < 4; ++st)
                    acc[qt][st] = __builtin_amdgcn_mfma_f32_16x16x32_bf16(a[qt], bb[st], acc[qt][st], 0, 0, 0);
        }
        // ---- per-query max/argmax over 64 slots; C layout: col=lane&15, row=(lane>>4)*4+reg
#pragma unroll
        for (int qt = 0; qt < 2; ++qt) {
#pragma unroll
            for (int reg = 0; reg < 4; ++reg) {
                float m = acc[qt][0][reg];
                int  mi = (lane & 15);
#pragma unroll
                for (int st = 1; st < 4; ++st) {
                    float vv = acc[qt][st][reg];
                    int   vi = st * 16 + (lane & 15);
                    if (vv > m) { m = vv; mi = vi; }
                }
#pragma unroll
                for (int delta = 1; delta < 16; delta <<= 1) {
                    float om = __shfl_xor(m, delta);
                    int   oi = __shfl_xor(mi, delta);
                    if (om > m || (om == m && oi < mi)) { m = om; mi = oi; }
                }
                if ((lane & 15) == 0) {
                    int qrow = (2 * wave + qt) * 16 + (lane >> 4) * 4 + reg;
                    scores_t[(size_t)r * NM + qrow] = m;
                    widx_t[(size_t)r * NM + qrow] = (unsigned char)mi;
                }
            }
        }
    }
}

// ----------------------------------------- K3: top-32 + exact attention + update
__global__ __launch_bounds__(256) void k3_topk_attn(
    const float* __restrict__ scores_t, const unsigned char* __restrict__ widx_t,
    const float* __restrict__ mkeys, const float* __restrict__ q_f32,
    const float* __restrict__ mask, const float* __restrict__ uw,
    const float* __restrict__ ub, float* __restrict__ upd)
{
    int q = blockIdx.x;
    int tid = threadIdx.x;
    int lane = tid & 63, wave = tid >> 6;
    __shared__ float sc[NROWS];          // 64KB
    __shared__ float cmax[256];
    __shared__ int   cidx[256];
    __shared__ int   toprows[KTOP];
    __shared__ float keys[KTOP][KD];     // 16KB
    __shared__ float sk[KTOP];
    __shared__ float attn[KTOP];
    __shared__ float retr[KD];
    __shared__ int   bestc;
    __shared__ float wval[4];
    __shared__ int   wchk[4];

    // load this query's row-score column
#pragma unroll 8
    for (int jj = 0; jj < 64; ++jj) {
        int i = jj * 256 + tid;
        sc[i] = scores_t[(size_t)i * NM + q];
    }
    __syncthreads();
    // per-thread chunk maxima (chunk t = rows [64t, 64t+64)), staggered to dodge bank conflicts
    {
        float m = NEG_INF; int mi = 0;
        for (int jj = 0; jj < 64; ++jj) {
            int j = (jj + tid) & 63;
            int i = tid * 64 + j;
            float vv = sc[i];
            if (vv > m || (vv == m && i < mi)) { m = vv; mi = i; }
        }
        cmax[tid] = m; cidx[tid] = mi;
    }
    __syncthreads();
    for (int it = 0; it < KTOP; ++it) {
        float m = cmax[tid]; int c = tid;
#pragma unroll
        for (int delta = 1; delta < 64; delta <<= 1) {
            float om = __shfl_xor(m, delta);
            int   oc = __shfl_xor(c, delta);
            if (om > m || (om == m && oc < c)) { m = om; c = oc; }
        }
        if (lane == 0) { wval[wave] = m; wchk[wave] = c; }
        __syncthreads();
        if (tid == 0) {
            float bm = wval[0]; int bc = wchk[0];
            for (int w2 = 1; w2 < 4; ++w2)
                if (wval[w2] > bm || (wval[w2] == bm && wchk[w2] < bc)) { bm = wval[w2]; bc = wchk[w2]; }
            int row = cidx[bc];
            toprows[it] = row;
            sc[row] = NEG_INF;
            bestc = bc;
        }
        __syncthreads();
        if (wave == 0) {  // rebuild the winner chunk's max
            int bc = bestc;
            int i  = bc * 64 + lane;
            float m2 = sc[i]; int mi2 = i;
#pragma unroll
            for (int delta = 1; delta < 64; delta <<= 1) {
                float om = __shfl_xor(m2, delta);
                int   oi = __shfl_xor(mi2, delta);
                if (om > m2 || (om == m2 && oi < mi2)) { m2 = om; mi2 = oi; }
            }
            if (lane == 0) { cmax[bc] = m2; cidx[bc] = mi2; }
        }
        __syncthreads();
    }
    // gather the 32 selected keys
    for (int k = wave; k < KTOP; k += 4) {
        int row = toprows[k];
        int wid = widx_t[(size_t)row * NM + q];
        const float* kp = mkeys + ((size_t)row * VPR + wid) * KD;
        keys[k][lane]      = kp[lane];
        keys[k][lane + 64] = kp[lane + 64];
    }
    __syncthreads();
    // exact fp32 attention scores
    const float* qv = q_f32 + q * KD;
    for (int k = wave; k < KTOP; k += 4) {
        float p = qv[lane] * keys[k][lane] + qv[lane + 64] * keys[k][lane + 64];
#pragma unroll
        for (int delta = 1; delta < 64; delta <<= 1) p += __shfl_xor(p, delta);
        if (lane == 0) sk[k] = p;
    }
    __syncthreads();
    if (tid < 64) {  // softmax over 32
        float vv = (tid < KTOP) ? sk[tid] : NEG_INF;
        float mx = vv;
#pragma unroll
        for (int delta = 1; delta < 64; delta <<= 1) mx = fmaxf(mx, __shfl_xor(mx, delta));
        float e = (tid < KTOP) ? __expf(vv - mx) : 0.f;
        float ssum = e;
#pragma unroll
        for (int delta = 1; delta < 64; delta <<= 1) ssum += __shfl_xor(ssum, delta);
        if (tid < KTOP) attn[tid] = e / ssum;
    }
    __syncthreads();
    if (tid < KD) {
        float rsum = 0.f;
#pragma unroll
        for (int k = 0; k < KTOP; ++k) rsum = fmaf(attn[k], keys[k][tid], rsum);
        retr[tid] = rsum * mask[q];
    }
    __syncthreads();
    {   // update = retrieved @ update_w + update_b   (768 outputs, 3 per thread)
        float u0 = ub[tid], u1 = ub[tid + 256], u2 = ub[tid + 512];
        for (int kd2 = 0; kd2 < KD; ++kd2) {
            float rv = retr[kd2];
            const float* wr = uw + (size_t)kd2 * HD;
            u0 = fmaf(rv, wr[tid],       u0);
            u1 = fmaf(rv, wr[tid + 256], u1);
            u2 = fmaf(rv, wr[tid + 512], u2);
        }
        upd[(size_t)q * HD + tid]       = u0;
        upd[(size_t)q * HD + tid + 256] = u1;
        upd[(size_t)q * HD + tid + 512] = u2;
    }
}

// ---------------------------------------------------- K4: scatter-add + LayerNorm
__global__ __launch_bounds__(256) void k4_scatter_ln(
    const float* __restrict__ enc, const int* __restrict__ mb, const int* __restrict__ msp,
    const float* __restrict__ upd, const float* __restrict__ gamma,
    const float* __restrict__ beta, float* __restrict__ out)
{
    int tok = blockIdx.x;
    int b = tok >> 9, t = tok & 511;
    int tid = threadIdx.x;
    int lane = tid & 63, wave = tid >> 6;
    __shared__ int mbs[NM], mss[NM];
    if (tid < NM) { mbs[tid] = mb[tid]; mss[tid] = msp[tid]; }
    __syncthreads();
    const float* x = enc + (size_t)tok * HD;
    float x0 = x[tid], x1 = x[tid + 256], x2 = x[tid + 512];
    for (int q = 0; q < NM; ++q) {
        if (mbs[q] == b && mss[q] == t) {   // wave-uniform branch
            const float* u = upd + (size_t)q * HD;
            x0 += u[tid]; x1 += u[tid + 256]; x2 += u[tid + 512];
        }
    }
    __shared__ float redA[4], redB[4];
    float s = x0 + x1 + x2;
#pragma unroll
    for (int delta = 1; delta < 64; delta <<= 1) s += __shfl_xor(s, delta);
    if (lane == 0) redA[wave] = s;
    __syncthreads();
    float mu = (redA[0] + redA[1] + redA[2] + redA[3]) * (1.f / 768.f);
    float d0 = x0 - mu, d1 = x1 - mu, d2 = x2 - mu;
    float s2 = d0 * d0 + d1 * d1 + d2 * d2;
#pragma unroll
    for (int delta = 1; delta < 64; delta <<= 1) s2 += __shfl_xor(s2, delta);
    if (lane == 0) redB[wave] = s2;
    __syncthreads();
    float var = (redB[0] + redB[1] + redB[2] + redB[3]) * (1.f / 768.f);
    float rs = rsqrtf(var + 1e-12f);
    float* o = out + (size_t)tok * HD;
    o[tid]       = d0 * rs * gamma[tid]       + beta[tid];
    o[tid + 256] = d1 * rs * gamma[tid + 256] + beta[tid + 256];
    o[tid + 512] = d2 * rs * gamma[tid + 512] + beta[tid + 512];
}

// --------------------------------------------------------------------- launch
extern "C" void kernel_launch(void* const* d_in, const int* in_sizes, int n_in,
                              void* d_out, int out_size, void* d_ws, size_t ws_size,
                              hipStream_t stream) {
    const float* enc   = (const float*)d_in[0];
    const int*   mb    = (const int*)d_in[1];
    const int*   msp   = (const int*)d_in[2];
    const int*   mep   = (const int*)d_in[3];
    const float* mask  = (const float*)d_in[4];
    const float* mkeys = (const float*)d_in[5];
    // d_in[6] memory_entity_ids: unused by the output
    const float* qw    = (const float*)d_in[7];
    const float* qb    = (const float*)d_in[8];
    const float* uw    = (const float*)d_in[9];
    const float* ub    = (const float*)d_in[10];
    const float* gamma = (const float*)d_in[11];
    const float* beta  = (const float*)d_in[12];
    float* out = (float*)d_out;

    char* ws = (char*)d_ws;
    float*          q_f32    = (float*)(ws);                       //  64 KB
    unsigned short* q_bf16   = (unsigned short*)(ws + 65536);      //  32 KB
    float*          upd      = (float*)(ws + 98304);               // 384 KB
    float*          scores_t = (float*)(ws + 491520);              //   8 MB  [row][q]
    unsigned char*  widx_t   = (unsigned char*)(ws + 8880128);     //   2 MB  [row][q]

    k1_queries<<<dim3(NM), dim3(256), 0, stream>>>(enc, mb, msp, mep, qw, qb, q_f32, q_bf16);
    k2_scores<<<dim3(K2_BLOCKS), dim3(256), 0, stream>>>(mkeys, q_bf16, scores_t, widx_t);
    k3_topk_attn<<<dim3(NM), dim3(256), 0, stream>>>(scores_t, widx_t, mkeys, q_f32, mask, uw, ub, upd);
    k4_scatter_ln<<<dim3(4 * TT), dim3(256), 0, stream>>>(enc, mb, msp, upd, gamma, beta, out);
}

// Round 7
// 862.770 us; speedup vs baseline: 1.0198x; 1.0198x over previous
//
#include <hip/hip_runtime.h>
#include <hip/hip_bf16.h>

#define NM 128        // n_mentions / queries
#define HD 768        // hidden
#define TT 512        // tokens per batch
#define KD 128        // key dim
#define NROWS 16384   // memory rows
#define VPR 64        // values per row
#define KTOP 32
#define K2_BLOCKS 2048
#define TR_ROWS 64
#define NEG_INF -3.402823466e38f

typedef __bf16 bf16x8 __attribute__((ext_vector_type(8)));
typedef float  f32x4  __attribute__((ext_vector_type(4)));

__device__ __forceinline__ unsigned short f2bf(float f) {
    __bf16 h = (__bf16)f;
    return __builtin_bit_cast(unsigned short, h);
}

// ---------------------------------------------------------------- K1: queries
__global__ __launch_bounds__(256) void k1_queries(
    const float* __restrict__ enc, const int* __restrict__ mb,
    const int* __restrict__ msp, const int* __restrict__ mep,
    const float* __restrict__ qw, const float* __restrict__ qb,
    float* __restrict__ q_f32, unsigned short* __restrict__ q_bf16)
{
    int q = blockIdx.x;
    int b = mb[q], s = msp[q], e = mep[q];
    __shared__ float encs[2 * HD];
    const float* srow = enc + ((size_t)b * TT + s) * HD;
    const float* erow = enc + ((size_t)b * TT + e) * HD;
    for (int i = threadIdx.x; i < HD; i += 256) {
        encs[i]      = srow[i];
        encs[HD + i] = erow[i];
    }
    __syncthreads();
    int d = threadIdx.x & 127;
    int h = threadIdx.x >> 7;           // 0 = start half, 1 = end half
    const float* w  = qw + (size_t)(h * HD) * KD + d;
    const float* ev = encs + h * HD;
    float acc = 0.f;
#pragma unroll 8
    for (int i = 0; i < HD; ++i) acc = fmaf(ev[i], w[(size_t)i * KD], acc);
    __shared__ float part[256];
    part[threadIdx.x] = acc;
    __syncthreads();
    if (threadIdx.x < 128) {
        float v = part[threadIdx.x] + part[threadIdx.x + 128] + qb[d];
        q_f32[q * KD + d] = v;
        // bf16 copy in the (swizzled) LDS A-operand layout K2 will memcpy
        unsigned byteoff = ((unsigned)(q * 256 + d * 2)) ^ (((unsigned)(q & 7)) << 4);
        q_bf16[byteoff >> 1] = f2bf(v);
    }
}

// ------------------------------------------------- K2: scores + row max/argmax
// Prefetch structure: registers v[] hold row r's data at loop top (loaded last
// iteration). Convert->LDS, barrier, then immediately issue loads for r+stride
// so the ~900cy HBM latency hides under MFMA+argmax+stores. The vmcnt(0) drain
// at the next iteration's __syncthreads lands after ~1000+cy of cover.
__global__ __launch_bounds__(256, 3) void k2_scores(
    const float* __restrict__ mkeys, const unsigned short* __restrict__ q_bf16,
    float* __restrict__ scores_t, unsigned char* __restrict__ widx_t)
{
    __shared__ __attribute__((aligned(16))) unsigned short qs[NM * KD];  // 32KB swizzled
    __shared__ __attribute__((aligned(16))) unsigned short ks[VPR * KD]; // 16KB swizzled
    {   // queries: global layout already matches LDS layout -> linear copy
        const uint4* src = (const uint4*)q_bf16;
        uint4* dst = (uint4*)qs;
#pragma unroll
        for (int i = 0; i < 8; ++i) dst[i * 256 + threadIdx.x] = src[i * 256 + threadIdx.x];
    }
    int tid = threadIdx.x;
    int lane = tid & 63;
    int wave = tid >> 6;

    float4 v[8];
    {   // prefetch first row
        const float4* s0 = (const float4*)(mkeys + (size_t)blockIdx.x * (VPR * KD));
#pragma unroll
        for (int i = 0; i < 8; ++i) v[i] = s0[i * 256 + tid];
    }

    for (int r = blockIdx.x; r < NROWS; r += K2_BLOCKS) {
        __syncthreads();  // B1: prev iter's ks readers done (also covers qs copy)
        // ---- convert row r (already in regs) -> bf16 swizzled LDS
#pragma unroll
        for (int i = 0; i < 8; ++i) {
            int fidx = (i * 256 + tid) * 4;
            int slot = fidx >> 7, dd = fidx & 127;
            ushort4 u;
            u.x = f2bf(v[i].x); u.y = f2bf(v[i].y);
            u.z = f2bf(v[i].z); u.w = f2bf(v[i].w);
            unsigned byteoff = ((unsigned)(slot * 256 + dd * 2)) ^ (((unsigned)(slot & 7)) << 4);
            *(ushort4*)((char*)ks + byteoff) = u;
        }
        __syncthreads();  // B2: ks ready
        // ---- issue next row's loads now; they fly under the MFMA/argmax below
        int rn = r + K2_BLOCKS;
        if (rn < NROWS) {  // uniform across block (NROWS % K2_BLOCKS == 0)
            const float4* s1 = (const float4*)(mkeys + (size_t)rn * (VPR * KD));
#pragma unroll
            for (int i = 0; i < 8; ++i) v[i] = s1[i * 256 + tid];
        }
        // ---- MFMA: wave handles q-tiles {2w,2w+1} x slot-tiles {0..3}
        f32x4 acc[2][4];
        f32x4 zero = {0.f, 0.f, 0.f, 0.f};
#pragma unroll
        for (int qt = 0; qt < 2; ++qt)
#pragma unroll
            for (int st = 0; st < 4; ++st) acc[qt][st] = zero;
#pragma unroll
        for (int kk = 0; kk < 4; ++kk) {
            int kbase = kk * 32 + (lane >> 4) * 8;
            bf16x8 a[2], bb[4];
#pragma unroll
            for (int qt = 0; qt < 2; ++qt) {
                int qrow = (2 * wave + qt) * 16 + (lane & 15);
                unsigned byteoff = ((unsigned)(qrow * 256 + kbase * 2)) ^ (((unsigned)(qrow & 7)) << 4);
                a[qt] = *(const bf16x8*)((const char*)qs + byteoff);
            }
#pragma unroll
            for (int st = 0; st < 4; ++st) {
                int slot = st * 16 + (lane & 15);
                unsigned byteoff = ((unsigned)(slot * 256 + kbase * 2)) ^ (((unsigned)(slot & 7)) << 4);
                bb[st] = *(const bf16x8*)((const char*)ks + byteoff);
            }
#pragma unroll
            for (int qt = 0; qt < 2; ++qt)
#pragma unroll
                for (int st = 0; st < 4; ++st)
                    acc[qt][st] = __builtin_amdgcn_mfma_f32_16x16x32_bf16(a[qt], bb[st], acc[qt][st], 0, 0, 0);
        }
        // ---- per-query max/argmax over 64 slots; C layout: col=lane&15, row=(lane>>4)*4+reg
#pragma unroll
        for (int qt = 0; qt < 2; ++qt) {
#pragma unroll
            for (int reg = 0; reg < 4; ++reg) {
                float m = acc[qt][0][reg];
                int  mi = (lane & 15);
#pragma unroll
                for (int st = 1; st < 4; ++st) {
                    float vv = acc[qt][st][reg];
                    int   vi = st * 16 + (lane & 15);
                    if (vv > m) { m = vv; mi = vi; }
                }
#pragma unroll
                for (int delta = 1; delta < 16; delta <<= 1) {
                    float om = __shfl_xor(m, delta);
                    int   oi = __shfl_xor(mi, delta);
                    if (om > m || (om == m && oi < mi)) { m = om; mi = oi; }
                }
                if ((lane & 15) == 0) {
                    int qrow = (2 * wave + qt) * 16 + (lane >> 4) * 4 + reg;
                    scores_t[(size_t)r * NM + qrow] = m;
                    widx_t[(size_t)r * NM + qrow] = (unsigned char)mi;
                }
            }
        }
    }
}

// ------------------------------------- K2b: transpose scores [row][q]->[q][row]
__global__ __launch_bounds__(256) void k2b_transpose(
    const float* __restrict__ st, float* __restrict__ sq)
{
    __shared__ float tile[TR_ROWS][133];   // pad 133: write-back column reads 2-way max
    int r0 = blockIdx.x * TR_ROWS;
    int tid = threadIdx.x;
    const float4* src = (const float4*)(st + (size_t)r0 * NM);
#pragma unroll
    for (int i = 0; i < 8; ++i) {
        float4 f = src[i * 256 + tid];
        int fi = (i * 256 + tid) * 4;
        int rr = fi >> 7, q = fi & 127;
        tile[rr][q]     = f.x;
        tile[rr][q + 1] = f.y;
        tile[rr][q + 2] = f.z;
        tile[rr][q + 3] = f.w;
    }
    __syncthreads();
    int rr0 = (tid & 15) * 4;
#pragma unroll
    for (int j = 0; j < 8; ++j) {
        int q = j * 16 + (tid >> 4);
        float4 o;
        o.x = tile[rr0][q]; o.y = tile[rr0 + 1][q];
        o.z = tile[rr0 + 2][q]; o.w = tile[rr0 + 3][q];
        *(float4*)(sq + (size_t)q * NROWS + r0 + rr0) = o;
    }
}

// ----------------------------------------- K3: top-32 + exact attention + update
__global__ __launch_bounds__(256) void k3_topk_attn(
    const float* __restrict__ scores_q, const unsigned char* __restrict__ widx_t,
    const float* __restrict__ mkeys, const float* __restrict__ q_f32,
    const float* __restrict__ mask, const float* __restrict__ uw,
    const float* __restrict__ ub, float* __restrict__ upd)
{
    int q = blockIdx.x;
    int tid = threadIdx.x;
    int lane = tid & 63, wave = tid >> 6;
    __shared__ float sc[NROWS];          // 64KB
    __shared__ float cmax[256];
    __shared__ int   cidx[256];
    __shared__ int   toprows[KTOP];
    __shared__ float keys[KTOP][KD];     // 16KB
    __shared__ float sk[KTOP];
    __shared__ float attn[KTOP];
    __shared__ float retr[KD];
    __shared__ int   bestc;
    __shared__ float wval[4];
    __shared__ int   wchk[4];

    // load this query's row-score vector (coalesced, thanks to K2b)
    {
        const float4* srcq = (const float4*)(scores_q + (size_t)q * NROWS);
#pragma unroll
        for (int jj = 0; jj < 16; ++jj) {
            float4 f = srcq[jj * 256 + tid];
            int i = (jj * 256 + tid) * 4;
            *(float4*)(sc + i) = f;
        }
    }
    __syncthreads();
    // per-thread chunk maxima (chunk t = rows [64t, 64t+64)), staggered to dodge bank conflicts
    {
        float m = NEG_INF; int mi = 0;
        for (int jj = 0; jj < 64; ++jj) {
            int j = (jj + tid) & 63;
            int i = tid * 64 + j;
            float vv = sc[i];
            if (vv > m || (vv == m && i < mi)) { m = vv; mi = i; }
        }
        cmax[tid] = m; cidx[tid] = mi;
    }
    __syncthreads();
    for (int it = 0; it < KTOP; ++it) {
        float m = cmax[tid]; int c = tid;
#pragma unroll
        for (int delta = 1; delta < 64; delta <<= 1) {
            float om = __shfl_xor(m, delta);
            int   oc = __shfl_xor(c, delta);
            if (om > m || (om == m && oc < c)) { m = om; c = oc; }
        }
        if (lane == 0) { wval[wave] = m; wchk[wave] = c; }
        __syncthreads();
        if (tid == 0) {
            float bm = wval[0]; int bc = wchk[0];
            for (int w2 = 1; w2 < 4; ++w2)
                if (wval[w2] > bm || (wval[w2] == bm && wchk[w2] < bc)) { bm = wval[w2]; bc = wchk[w2]; }
            int row = cidx[bc];
            toprows[it] = row;
            sc[row] = NEG_INF;
            bestc = bc;
        }
        __syncthreads();
        if (wave == 0) {  // rebuild the winner chunk's max
            int bc = bestc;
            int i  = bc * 64 + lane;
            float m2 = sc[i]; int mi2 = i;
#pragma unroll
            for (int delta = 1; delta < 64; delta <<= 1) {
                float om = __shfl_xor(m2, delta);
                int   oi = __shfl_xor(mi2, delta);
                if (om > m2 || (om == m2 && oi < mi2)) { m2 = om; mi2 = oi; }
            }
            if (lane == 0) { cmax[bc] = m2; cidx[bc] = mi2; }
        }
        __syncthreads();
    }
    // gather the 32 selected keys
    for (int k = wave; k < KTOP; k += 4) {
        int row = toprows[k];
        int wid = widx_t[(size_t)row * NM + q];
        const float* kp = mkeys + ((size_t)row * VPR + wid) * KD;
        keys[k][lane]      = kp[lane];
        keys[k][lane + 64] = kp[lane + 64];
    }
    __syncthreads();
    // exact fp32 attention scores
    const float* qv = q_f32 + q * KD;
    for (int k = wave; k < KTOP; k += 4) {
        float p = qv[lane] * keys[k][lane] + qv[lane + 64] * keys[k][lane + 64];
#pragma unroll
        for (int delta = 1; delta < 64; delta <<= 1) p += __shfl_xor(p, delta);
        if (lane == 0) sk[k] = p;
    }
    __syncthreads();
    if (tid < 64) {  // softmax over 32
        float vv = (tid < KTOP) ? sk[tid] : NEG_INF;
        float mx = vv;
#pragma unroll
        for (int delta = 1; delta < 64; delta <<= 1) mx = fmaxf(mx, __shfl_xor(mx, delta));
        float e = (tid < KTOP) ? __expf(vv - mx) : 0.f;
        float ssum = e;
#pragma unroll
        for (int delta = 1; delta < 64; delta <<= 1) ssum += __shfl_xor(ssum, delta);
        if (tid < KTOP) attn[tid] = e / ssum;
    }
    __syncthreads();
    if (tid < KD) {
        float rsum = 0.f;
#pragma unroll
        for (int k = 0; k < KTOP; ++k) rsum = fmaf(attn[k], keys[k][tid], rsum);
        retr[tid] = rsum * mask[q];
    }
    __syncthreads();
    {   // update = retrieved @ update_w + update_b   (768 outputs, 3 per thread)
        float u0 = ub[tid], u1 = ub[tid + 256], u2 = ub[tid + 512];
        for (int kd2 = 0; kd2 < KD; ++kd2) {
            float rv = retr[kd2];
            const float* wr = uw + (size_t)kd2 * HD;
            u0 = fmaf(rv, wr[tid],       u0);
            u1 = fmaf(rv, wr[tid + 256], u1);
            u2 = fmaf(rv, wr[tid + 512], u2);
        }
        upd[(size_t)q * HD + tid]       = u0;
        upd[(size_t)q * HD + tid + 256] = u1;
        upd[(size_t)q * HD + tid + 512] = u2;
    }
}

// ---------------------------------------------------- K4: scatter-add + LayerNorm
__global__ __launch_bounds__(256) void k4_scatter_ln(
    const float* __restrict__ enc, const int* __restrict__ mb, const int* __restrict__ msp,
    const float* __restrict__ upd, const float* __restrict__ gamma,
    const float* __restrict__ beta, float* __restrict__ out)
{
    int tok = blockIdx.x;
    int b = tok >> 9, t = tok & 511;
    int tid = threadIdx.x;
    int lane = tid & 63, wave = tid >> 6;
    __shared__ int mbs[NM], mss[NM];
    if (tid < NM) { mbs[tid] = mb[tid]; mss[tid] = msp[tid]; }
    __syncthreads();
    const float* x = enc + (size_t)tok * HD;
    float x0 = x[tid], x1 = x[tid + 256], x2 = x[tid + 512];
    for (int q = 0; q < NM; ++q) {
        if (mbs[q] == b && mss[q] == t) {   // wave-uniform branch
            const float* u = upd + (size_t)q * HD;
            x0 += u[tid]; x1 += u[tid + 256]; x2 += u[tid + 512];
        }
    }
    __shared__ float redA[4], redB[4];
    float s = x0 + x1 + x2;
#pragma unroll
    for (int delta = 1; delta < 64; delta <<= 1) s += __shfl_xor(s, delta);
    if (lane == 0) redA[wave] = s;
    __syncthreads();
    float mu = (redA[0] + redA[1] + redA[2] + redA[3]) * (1.f / 768.f);
    float d0 = x0 - mu, d1 = x1 - mu, d2 = x2 - mu;
    float s2 = d0 * d0 + d1 * d1 + d2 * d2;
#pragma unroll
    for (int delta = 1; delta < 64; delta <<= 1) s2 += __shfl_xor(s2, delta);
    if (lane == 0) redB[wave] = s2;
    __syncthreads();
    float var = (redB[0] + redB[1] + redB[2] + redB[3]) * (1.f / 768.f);
    float rs = rsqrtf(var + 1e-12f);
    float* o = out + (size_t)tok * HD;
    o[tid]       = d0 * rs * gamma[tid]       + beta[tid];
    o[tid + 256] = d1 * rs * gamma[tid + 256] + beta[tid + 256];
    o[tid + 512] = d2 * rs * gamma[tid + 512] + beta[tid + 512];
}

// --------------------------------------------------------------------- launch
extern "C" void kernel_launch(void* const* d_in, const int* in_sizes, int n_in,
                              void* d_out, int out_size, void* d_ws, size_t ws_size,
                              hipStream_t stream) {
    const float* enc   = (const float*)d_in[0];
    const int*   mb    = (const int*)d_in[1];
    const int*   msp   = (const int*)d_in[2];
    const int*   mep   = (const int*)d_in[3];
    const float* mask  = (const float*)d_in[4];
    const float* mkeys = (const float*)d_in[5];
    // d_in[6] memory_entity_ids: unused by the output
    const float* qw    = (const float*)d_in[7];
    const float* qb    = (const float*)d_in[8];
    const float* uw    = (const float*)d_in[9];
    const float* ub    = (const float*)d_in[10];
    const float* gamma = (const float*)d_in[11];
    const float* beta  = (const float*)d_in[12];
    float* out = (float*)d_out;

    char* ws = (char*)d_ws;
    float*          q_f32    = (float*)(ws);                       //  64 KB
    unsigned short* q_bf16   = (unsigned short*)(ws + 65536);      //  32 KB
    float*          upd      = (float*)(ws + 98304);               // 384 KB
    float*          scores_t = (float*)(ws + 491520);              //   8 MB  [row][q]
    unsigned char*  widx_t   = (unsigned char*)(ws + 8880128);     //   2 MB  [row][q]
    float*          scores_q = (float*)(ws + 10977280);            //   8 MB  [q][row]

    k1_queries<<<dim3(NM), dim3(256), 0, stream>>>(enc, mb, msp, mep, qw, qb, q_f32, q_bf16);
    k2_scores<<<dim3(K2_BLOCKS), dim3(256), 0, stream>>>(mkeys, q_bf16, scores_t, widx_t);
    k2b_transpose<<<dim3(NROWS / TR_ROWS), dim3(256), 0, stream>>>(scores_t, scores_q);
    k3_topk_attn<<<dim3(NM), dim3(256), 0, stream>>>(scores_q, widx_t, mkeys, q_f32, mask, uw, ub, upd);
    k4_scatter_ln<<<dim3(4 * TT), dim3(256), 0, stream>>>(enc, mb, msp, upd, gamma, beta, out);
}